// Round 1
// baseline (310.296 us; speedup 1.0000x reference)
//
#include <hip/hip_runtime.h>
#include <hip/hip_bf16.h>

// AttentivePooling: B=32, S=8192, C=256, MID=128, all fp32.
// out[b,c] = sum_s softmax_s( tanh(x@W1+b1)@w2 )[b,s] * x[b,s,c]
// b2 dropped: uniform shift is softmax-invariant.
//
// ws layout: attn/scores = [0, 1MB); partials = [1MB, 5MB). Requires ws >= 5MB.

constexpr int Bb = 32;
constexpr int Ss = 8192;
constexpr int Cc = 256;
constexpr int MIDm = 128;
constexpr int BM = 128;          // rows per block (kernel A)
constexpr int BK = 32;           // k-chunk (kernel A)
constexpr int NSPLIT = 128;      // s-splits (kernel C)
constexpr int SCHUNK = Ss / NSPLIT;  // 64

// ---------------- Kernel A: scores = tanh(x@W1 + b1) @ w2 ----------------
// 256 threads, block tile 128 rows x 128 cols (full MID), 8x8 per-thread tile.
// tn = tid&15 owns cols {tn+16j}, tm = tid>>4 owns rows {tm+16i}.
__global__ __launch_bounds__(256) void scores_kernel(
    const float* __restrict__ x, const float* __restrict__ W1,
    const float* __restrict__ b1, const float* __restrict__ w2,
    float* __restrict__ scores)
{
  __shared__ float sX[BM][36];     // +4 pad: conflict-free b128 reads, 16B-aligned rows
  __shared__ float sW[BK][MIDm];   // linear; strided b32 reads are conflict-free

  const int tid = threadIdx.x;
  const int tn = tid & 15;
  const int tm = tid >> 4;
  const int row0 = blockIdx.x * BM;

  float acc[8][8];
  #pragma unroll
  for (int j = 0; j < 8; ++j) {
    float bj = b1[tn + 16 * j];
    #pragma unroll
    for (int i = 0; i < 8; ++i) acc[i][j] = bj;
  }

  for (int kc = 0; kc < Cc / BK; ++kc) {
    const int k0 = kc * BK;
    // stage x tile: 128 rows x 32 cols, 1024 float4 loads (coalesced 128B/row-group)
    #pragma unroll
    for (int l = 0; l < 4; ++l) {
      int idx = tid + l * 256;
      int r = idx >> 3;
      int f = idx & 7;
      float4 v = *(const float4*)&x[(row0 + r) * Cc + k0 + f * 4];
      *(float4*)&sX[r][f * 4] = v;
    }
    // stage W1 tile: rows k0..k0+31 x 128 cols = contiguous 4096 floats
    #pragma unroll
    for (int l = 0; l < 4; ++l) {
      int idx = tid + l * 256;
      float4 v = *(const float4*)&W1[k0 * MIDm + idx * 4];
      *(float4*)(&sW[0][0] + idx * 4) = v;
    }
    __syncthreads();

    #pragma unroll
    for (int kk = 0; kk < BK; kk += 4) {
      float4 xf[8];
      #pragma unroll
      for (int i = 0; i < 8; ++i)
        xf[i] = *(const float4*)&sX[tm + 16 * i][kk];
      #pragma unroll
      for (int kq = 0; kq < 4; ++kq) {
        float wq[8];
        #pragma unroll
        for (int j = 0; j < 8; ++j) wq[j] = sW[kk + kq][tn + 16 * j];
        #pragma unroll
        for (int i = 0; i < 8; ++i) {
          float xv = ((const float*)&xf[i])[kq];
          #pragma unroll
          for (int j = 0; j < 8; ++j)
            acc[i][j] = fmaf(xv, wq[j], acc[i][j]);
        }
      }
    }
    __syncthreads();
  }

  // epilogue: score = sum_m tanh(h_m) * w2_m ; reduce over the 16 tn lanes
  float w2r[8];
  #pragma unroll
  for (int j = 0; j < 8; ++j) w2r[j] = w2[tn + 16 * j];

  #pragma unroll
  for (int i = 0; i < 8; ++i) {
    float p = 0.f;
    #pragma unroll
    for (int j = 0; j < 8; ++j) p += tanhf(acc[i][j]) * w2r[j];
    #pragma unroll
    for (int off = 1; off < 16; off <<= 1) p += __shfl_xor(p, off);
    if (tn == 0) scores[row0 + tm + 16 * i] = p;
  }
}

// ---------------- Kernel B: in-place softmax over S per batch ----------------
__global__ __launch_bounds__(1024) void softmax_kernel(float* __restrict__ attn)
{
  const int b = blockIdx.x;
  float* sc = attn + (size_t)b * Ss;
  const int tid = threadIdx.x;
  __shared__ float red[16];

  float v[8];
  float mx = -3.4e38f;
  #pragma unroll
  for (int i = 0; i < 8; ++i) { v[i] = sc[tid + i * 1024]; mx = fmaxf(mx, v[i]); }
  #pragma unroll
  for (int off = 1; off < 64; off <<= 1) mx = fmaxf(mx, __shfl_xor(mx, off));
  if ((tid & 63) == 0) red[tid >> 6] = mx;
  __syncthreads();
  #pragma unroll
  for (int w = 0; w < 16; ++w) mx = fmaxf(mx, red[w]);

  float s = 0.f;
  #pragma unroll
  for (int i = 0; i < 8; ++i) { v[i] = expf(v[i] - mx); s += v[i]; }
  #pragma unroll
  for (int off = 1; off < 64; off <<= 1) s += __shfl_xor(s, off);
  __syncthreads();                 // everyone done reading red (max phase)
  if ((tid & 63) == 0) red[tid >> 6] = s;
  __syncthreads();
  float tot = 0.f;
  #pragma unroll
  for (int w = 0; w < 16; ++w) tot += red[w];
  const float inv = 1.0f / tot;
  #pragma unroll
  for (int i = 0; i < 8; ++i) sc[tid + i * 1024] = v[i] * inv;
}

// ---------------- Kernel C: partial weighted sums over s-splits ----------------
__global__ __launch_bounds__(64) void wsum_kernel(
    const float* __restrict__ x, const float* __restrict__ attn,
    float* __restrict__ partial)
{
  const int split = blockIdx.x;
  const int b = blockIdx.y;
  const int t = threadIdx.x;   // 64 threads, each owns 4 channels (float4)
  const float* xr = x + ((size_t)b * Ss + (size_t)split * SCHUNK) * Cc;
  const float* at = attn + (size_t)b * Ss + (size_t)split * SCHUNK;
  float4 acc = make_float4(0.f, 0.f, 0.f, 0.f);
  #pragma unroll 4
  for (int s = 0; s < SCHUNK; ++s) {
    float a = at[s];
    float4 xv = *(const float4*)&xr[(size_t)s * Cc + t * 4];
    acc.x = fmaf(a, xv.x, acc.x);
    acc.y = fmaf(a, xv.y, acc.y);
    acc.z = fmaf(a, xv.z, acc.z);
    acc.w = fmaf(a, xv.w, acc.w);
  }
  *(float4*)&partial[((size_t)(b * NSPLIT + split)) * Cc + t * 4] = acc;
}

// ---------------- Kernel D: deterministic final reduce ----------------
__global__ __launch_bounds__(256) void reduce_kernel(
    const float* __restrict__ partial, float* __restrict__ out)
{
  const int b = blockIdx.x;
  const int c = threadIdx.x;
  float s = 0.f;
  for (int p = 0; p < NSPLIT; ++p)
    s += partial[((size_t)(b * NSPLIT + p)) * Cc + c];
  out[b * Cc + c] = s;
}

extern "C" void kernel_launch(void* const* d_in, const int* in_sizes, int n_in,
                              void* d_out, int out_size, void* d_ws, size_t ws_size,
                              hipStream_t stream)
{
  const float* x  = (const float*)d_in[0];
  const float* W1 = (const float*)d_in[1];
  const float* b1 = (const float*)d_in[2];
  const float* w2 = (const float*)d_in[3];
  // d_in[4] = b2: unused (softmax shift-invariant)
  float* out = (float*)d_out;

  float* attn    = (float*)d_ws;                          // B*S floats = 1 MB
  float* partial = (float*)((char*)d_ws + (1u << 20));    // B*NSPLIT*C floats = 4 MB

  scores_kernel<<<(Bb * Ss) / BM, 256, 0, stream>>>(x, W1, b1, w2, attn);
  softmax_kernel<<<Bb, 1024, 0, stream>>>(attn);
  wsum_kernel<<<dim3(NSPLIT, Bb), 64, 0, stream>>>(x, attn, partial);
  reduce_kernel<<<Bb, 256, 0, stream>>>(partial, out);
}

// Round 2
// 164.596 us; speedup vs baseline: 1.8852x; 1.8852x over previous
//
#include <hip/hip_runtime.h>
#include <hip/hip_bf16.h>

// AttentivePooling: B=32, S=8192, C=256, MID=128, fp32 in/out.
// out[b,c] = sum_s softmax_s( tanh(x@W1+b1)@w2 )[b,s] * x[b,s,c]   (b2 shift-invariant, dropped)
//
// Plan: bf16-split MFMA (hi*hi + hi*lo + lo*hi, fp32 accum) for the x@W1 GEMM,
// fused flash-style block-local softmax + weighted x sum, then a tiny combine.
// ws: WtH/WtL (pre-split W1^T, bf16) + per-block partials (o, m, l). ~2.2 MB.

typedef __attribute__((ext_vector_type(8))) short short8;
typedef __attribute__((ext_vector_type(4))) float f32x4;
typedef unsigned short u16;

constexpr int Bb = 32;
constexpr int Ss = 8192;
constexpr int Cc = 256;
constexpr int MIDm = 128;
constexpr int BM = 128;                 // rows per block
constexpr int NBLK = Bb * Ss / BM;      // 2048
constexpr int BPB = Ss / BM;            // 64 blocks per batch

__device__ __forceinline__ u16 f2bf(float f) {
  unsigned int u = __float_as_uint(f);
  u += 0x7FFFu + ((u >> 16) & 1u);
  return (u16)(u >> 16);
}
__device__ __forceinline__ float bf2f(u16 h) {
  return __uint_as_float(((unsigned int)h) << 16);
}

// ---- one-time prep: Wt[n][k] = W1[k][n] split into bf16 hi/lo ----
__global__ __launch_bounds__(256) void wprep_kernel(
    const float* __restrict__ W1, u16* __restrict__ WtH, u16* __restrict__ WtL)
{
  const int n = blockIdx.x;     // 0..127
  const int k = threadIdx.x;    // 0..255
  float f = W1[k * MIDm + n];
  u16 h = f2bf(f);
  u16 l = f2bf(f - bf2f(h));
  WtH[n * Cc + k] = h;
  WtL[n * Cc + k] = l;
}

// ---- fused: scores (MFMA) -> block softmax partials -> weighted x partial ----
// 256 threads = 4 waves (2M x 2N). Block: 128 rows x 128 mid, K=256 in 8 chunks of 32.
__global__ __launch_bounds__(256) void fused_kernel(
    const float* __restrict__ x, const u16* __restrict__ WtH, const u16* __restrict__ WtL,
    const float* __restrict__ b1, const float* __restrict__ w2,
    float* __restrict__ oPart, float* __restrict__ mPart, float* __restrict__ lPart)
{
  __shared__ __align__(16) u16 sXh[BM][40];   // pad to 40: uniform-bank b128 reads
  __shared__ __align__(16) u16 sXl[BM][40];
  __shared__ float sScore[2][BM];
  __shared__ float sP[BM];
  __shared__ float sMB, sLB;
  __shared__ __align__(16) float sO[4][Cc];

  const int tid  = threadIdx.x;
  const int lane = tid & 63;
  const int w    = tid >> 6;
  const int wr   = w >> 1;          // row half (0/1)
  const int wc   = w & 1;           // col half (0/1)
  const int q    = lane >> 4;       // 0..3 (k-group)
  const int ln   = lane & 15;       // frag row/col
  const int row0 = blockIdx.x * BM;

  // accumulators: 4 Mtiles x 4 Ntiles of 16x16, init with b1[col]
  f32x4 acc[4][4];
  #pragma unroll
  for (int nt = 0; nt < 4; ++nt) {
    float bj = b1[64 * wc + 16 * nt + ln];
    #pragma unroll
    for (int mt = 0; mt < 4; ++mt) {
      acc[mt][nt][0] = bj; acc[mt][nt][1] = bj; acc[mt][nt][2] = bj; acc[mt][nt][3] = bj;
    }
  }

  const int rr   = tid >> 1;    // staging row 0..127
  const int half = tid & 1;     // 16-col half of the 32-col chunk

  for (int kc = 0; kc < 8; ++kc) {
    // ---- stage x chunk: load fp32, split to bf16 hi/lo ----
    const float* xsrc = x + (size_t)(row0 + rr) * Cc + kc * 32 + half * 16;
    uint2 hh[4], ll[4];
    #pragma unroll
    for (int qq = 0; qq < 4; ++qq) {
      float4 v = *(const float4*)(xsrc + 4 * qq);
      u16 h0 = f2bf(v.x), h1 = f2bf(v.y), h2 = f2bf(v.z), h3 = f2bf(v.w);
      u16 l0 = f2bf(v.x - bf2f(h0)), l1 = f2bf(v.y - bf2f(h1));
      u16 l2 = f2bf(v.z - bf2f(h2)), l3 = f2bf(v.w - bf2f(h3));
      hh[qq].x = (unsigned)h0 | ((unsigned)h1 << 16);
      hh[qq].y = (unsigned)h2 | ((unsigned)h3 << 16);
      ll[qq].x = (unsigned)l0 | ((unsigned)l1 << 16);
      ll[qq].y = (unsigned)l2 | ((unsigned)l3 << 16);
    }
    __syncthreads();   // previous chunk's compute done
    #pragma unroll
    for (int qq = 0; qq < 4; ++qq) {
      *(uint2*)&sXh[rr][half * 16 + 4 * qq] = hh[qq];
      *(uint2*)&sXl[rr][half * 16 + 4 * qq] = ll[qq];
    }
    __syncthreads();

    // ---- compute: A-frags from LDS, B-frags from L2-resident Wt ----
    short8 ah[4], al[4];
    #pragma unroll
    for (int mt = 0; mt < 4; ++mt) {
      const int rw = 64 * wr + 16 * mt + ln;
      ah[mt] = *(const short8*)&sXh[rw][q * 8];
      al[mt] = *(const short8*)&sXl[rw][q * 8];
    }
    #pragma unroll
    for (int nt = 0; nt < 4; ++nt) {
      const size_t wo = (size_t)(64 * wc + 16 * nt + ln) * Cc + kc * 32 + q * 8;
      short8 bh = *(const short8*)(WtH + wo);
      short8 bl = *(const short8*)(WtL + wo);
      #pragma unroll
      for (int mt = 0; mt < 4; ++mt) {
        acc[mt][nt] = __builtin_amdgcn_mfma_f32_16x16x32_bf16(ah[mt], bh, acc[mt][nt], 0, 0, 0);
        acc[mt][nt] = __builtin_amdgcn_mfma_f32_16x16x32_bf16(ah[mt], bl, acc[mt][nt], 0, 0, 0);
        acc[mt][nt] = __builtin_amdgcn_mfma_f32_16x16x32_bf16(al[mt], bh, acc[mt][nt], 0, 0, 0);
      }
    }
  }

  // ---- epilogue: score[r] = sum_col tanh(h)*w2[col] ----
  float w2v[4];
  #pragma unroll
  for (int nt = 0; nt < 4; ++nt) w2v[nt] = w2[64 * wc + 16 * nt + ln];

  float p[4][4];   // [mt][reg] partial row sums over this wave's 64 cols
  #pragma unroll
  for (int mt = 0; mt < 4; ++mt)
    #pragma unroll
    for (int r = 0; r < 4; ++r) p[mt][r] = 0.f;

  #pragma unroll
  for (int mt = 0; mt < 4; ++mt)
    #pragma unroll
    for (int nt = 0; nt < 4; ++nt)
      #pragma unroll
      for (int r = 0; r < 4; ++r)
        p[mt][r] += tanhf(acc[mt][nt][r]) * w2v[nt];

  #pragma unroll
  for (int off = 1; off < 16; off <<= 1)
    #pragma unroll
    for (int mt = 0; mt < 4; ++mt)
      #pragma unroll
      for (int r = 0; r < 4; ++r)
        p[mt][r] += __shfl_xor(p[mt][r], off);

  if (ln == 0) {
    #pragma unroll
    for (int mt = 0; mt < 4; ++mt)
      #pragma unroll
      for (int r = 0; r < 4; ++r)
        sScore[wc][64 * wr + 16 * mt + 4 * q + r] = p[mt][r];
  }
  __syncthreads();

  // ---- block-local softmax partials ----
  if (tid < BM) sP[tid] = sScore[0][tid] + sScore[1][tid];   // raw scores
  __syncthreads();
  if (w == 0) {
    float a = sP[lane], b = sP[lane + 64];
    float m = fmaxf(a, b);
    #pragma unroll
    for (int off = 1; off < 64; off <<= 1) m = fmaxf(m, __shfl_xor(m, off));
    float e0 = __expf(a - m), e1 = __expf(b - m);
    sP[lane] = e0; sP[lane + 64] = e1;
    float s = e0 + e1;
    #pragma unroll
    for (int off = 1; off < 64; off <<= 1) s += __shfl_xor(s, off);
    if (lane == 0) { sMB = m; sLB = s; }
  }
  __syncthreads();

  // ---- weighted x partial: o[c] = sum_r sP[r] * x[row0+r][c] ----
  const int c4 = tid & 63;     // float4 column
  const int rg = tid >> 6;     // row group = wave
  const float* xo = x + (size_t)(row0 + rg * 32) * Cc + c4 * 4;
  float4 o = make_float4(0.f, 0.f, 0.f, 0.f);
  #pragma unroll 4
  for (int r = 0; r < 32; ++r) {
    float pw = sP[rg * 32 + r];
    float4 xv = *(const float4*)(xo + (size_t)r * Cc);
    o.x = fmaf(pw, xv.x, o.x);
    o.y = fmaf(pw, xv.y, o.y);
    o.z = fmaf(pw, xv.z, o.z);
    o.w = fmaf(pw, xv.w, o.w);
  }
  *(float4*)&sO[rg][c4 * 4] = o;
  __syncthreads();

  float oc = sO[0][tid] + sO[1][tid] + sO[2][tid] + sO[3][tid];
  oPart[(size_t)blockIdx.x * Cc + tid] = oc;
  if (tid == 0) { mPart[blockIdx.x] = sMB; lPart[blockIdx.x] = sLB; }
}

// ---- combine 64 block partials per batch (deterministic) ----
__global__ __launch_bounds__(256) void combine_kernel(
    const float* __restrict__ oPart, const float* __restrict__ mPart,
    const float* __restrict__ lPart, float* __restrict__ out)
{
  const int b = blockIdx.x;
  const int t = threadIdx.x;
  float M = -3.4e38f;
  for (int k = 0; k < BPB; ++k) M = fmaxf(M, mPart[b * BPB + k]);
  float num = 0.f, den = 0.f;
  for (int k = 0; k < BPB; ++k) {
    float wgt = __expf(mPart[b * BPB + k] - M);
    den += wgt * lPart[b * BPB + k];
    num = fmaf(wgt, oPart[(size_t)(b * BPB + k) * Cc + t], num);
  }
  out[b * Cc + t] = num / den;
}

extern "C" void kernel_launch(void* const* d_in, const int* in_sizes, int n_in,
                              void* d_out, int out_size, void* d_ws, size_t ws_size,
                              hipStream_t stream)
{
  const float* x  = (const float*)d_in[0];
  const float* W1 = (const float*)d_in[1];
  const float* b1 = (const float*)d_in[2];
  const float* w2 = (const float*)d_in[3];
  // d_in[4] = b2: unused (softmax shift-invariant)
  float* out = (float*)d_out;

  u16*   WtH   = (u16*)d_ws;                                   // 64 KB
  u16*   WtL   = WtH + MIDm * Cc;                              // 64 KB
  float* oPart = (float*)((char*)d_ws + 131072);               // 2 MB
  float* mPart = (float*)((char*)d_ws + 131072 + 2097152);     // 8 KB
  float* lPart = (float*)((char*)d_ws + 131072 + 2097152 + 8192);

  wprep_kernel<<<MIDm, Cc, 0, stream>>>(W1, WtH, WtL);
  fused_kernel<<<NBLK, 256, 0, stream>>>(x, WtH, WtL, b1, w2, oPart, mPart, lPart);
  combine_kernel<<<Bb, Cc, 0, stream>>>(oPart, mPart, lPart, out);
}

// Round 3
// 133.805 us; speedup vs baseline: 2.3190x; 1.2301x over previous
//
#include <hip/hip_runtime.h>
#include <hip/hip_bf16.h>

// AttentivePooling: B=32, S=8192, C=256, MID=128, fp32 in/out.
// out[b,c] = sum_s softmax_s( tanh(x@W1+b1)@w2 )[b,s] * x[b,s,c]   (b2 shift-invariant, dropped)
//
// R3: 2-term bf16 split (x_hi*W_hi + x_hi*W_lo), ping-pong LDS double buffer,
// register prefetch of next x chunk, 1 barrier/chunk, fast tanh.
// ws: WtH/WtL (pre-split W1^T bf16) + per-block partials (o, m, l).

typedef __attribute__((ext_vector_type(8))) short short8;
typedef __attribute__((ext_vector_type(4))) float f32x4;
typedef unsigned short u16;

constexpr int Bb = 32;
constexpr int Ss = 8192;
constexpr int Cc = 256;
constexpr int MIDm = 128;
constexpr int BM = 128;                 // rows per block
constexpr int NBLK = Bb * Ss / BM;      // 2048
constexpr int BPB = Ss / BM;            // 64 blocks per batch

__device__ __forceinline__ u16 f2bf(float f) {
  unsigned int u = __float_as_uint(f);
  u += 0x7FFFu + ((u >> 16) & 1u);
  return (u16)(u >> 16);
}
__device__ __forceinline__ float bf2f(u16 h) {
  return __uint_as_float(((unsigned int)h) << 16);
}
__device__ __forceinline__ float fast_tanh(float y) {
  return 1.0f - 2.0f / (__expf(2.0f * y) + 1.0f);
}

// ---- one-time prep: Wt[n][k] = W1[k][n] split into bf16 hi/lo ----
__global__ __launch_bounds__(256) void wprep_kernel(
    const float* __restrict__ W1, u16* __restrict__ WtH, u16* __restrict__ WtL)
{
  const int n = blockIdx.x;     // 0..127
  const int k = threadIdx.x;    // 0..255
  float f = W1[k * MIDm + n];
  u16 h = f2bf(f);
  u16 l = f2bf(f - bf2f(h));
  WtH[n * Cc + k] = h;
  WtL[n * Cc + k] = l;
}

// ---- fused: scores (MFMA) -> block softmax partials -> weighted x partial ----
// 256 threads = 4 waves (2M x 2N). Block: 128 rows x 128 mid, K=256 in 8 chunks of 32.
__global__ __launch_bounds__(256) void fused_kernel(
    const float* __restrict__ x, const u16* __restrict__ WtH, const u16* __restrict__ WtL,
    const float* __restrict__ b1, const float* __restrict__ w2,
    float* __restrict__ oPart, float* __restrict__ mPart, float* __restrict__ lPart)
{
  __shared__ __align__(16) u16 sXh[2][BM][40];   // ping-pong, pad 40 keeps b128 alignment
  __shared__ float sScore[2][BM];
  __shared__ float sP[BM];
  __shared__ float sMB, sLB;
  __shared__ __align__(16) float sO[4][Cc];

  const int tid  = threadIdx.x;
  const int lane = tid & 63;
  const int w    = tid >> 6;
  const int wr   = w >> 1;          // row half (0/1)
  const int wc   = w & 1;           // col half (0/1)
  const int q    = lane >> 4;       // 0..3 (k-group)
  const int ln   = lane & 15;       // frag row/col
  const int row0 = blockIdx.x * BM;

  // staging coords: each thread loads 16 floats of one row-half per chunk
  const int rr = tid >> 1;          // row 0..127
  const int hf = tid & 1;           // which 16-col half of the 32-col chunk

  // accumulators: 4 Mtiles x 4 Ntiles of 16x16, init with b1[col]
  f32x4 acc[4][4];
  #pragma unroll
  for (int nt = 0; nt < 4; ++nt) {
    float bj = b1[64 * wc + 16 * nt + ln];
    #pragma unroll
    for (int mt = 0; mt < 4; ++mt) {
      acc[mt][nt][0] = bj; acc[mt][nt][1] = bj; acc[mt][nt][2] = bj; acc[mt][nt][3] = bj;
    }
  }

  // ---- prologue: stage chunk 0 into buf 0 ----
  {
    const float* xs = x + (size_t)(row0 + rr) * Cc + hf * 16;
    #pragma unroll
    for (int qq = 0; qq < 4; ++qq) {
      float4 v = *(const float4*)(xs + 4 * qq);
      uint2 hh;
      hh.x = (unsigned)f2bf(v.x) | ((unsigned)f2bf(v.y) << 16);
      hh.y = (unsigned)f2bf(v.z) | ((unsigned)f2bf(v.w) << 16);
      *(uint2*)&sXh[0][rr][hf * 16 + 4 * qq] = hh;
    }
  }
  __syncthreads();

  for (int kc = 0; kc < 8; ++kc) {
    const int cur = kc & 1;

    // ---- issue prefetch of next chunk (registers; latency hides under MFMA) ----
    float4 xn[4];
    if (kc < 7) {
      const float* xs = x + (size_t)(row0 + rr) * Cc + (kc + 1) * 32 + hf * 16;
      #pragma unroll
      for (int qq = 0; qq < 4; ++qq) xn[qq] = *(const float4*)(xs + 4 * qq);
    }

    // ---- A frags from LDS ----
    short8 ah[4];
    #pragma unroll
    for (int mt = 0; mt < 4; ++mt)
      ah[mt] = *(const short8*)&sXh[cur][64 * wr + 16 * mt + ln][q * 8];

    // ---- B frags from L2-resident Wt (all issued up front) ----
    const size_t wbase = (size_t)(64 * wc + ln) * Cc + kc * 32 + q * 8;
    short8 bh[4], bl[4];
    #pragma unroll
    for (int nt = 0; nt < 4; ++nt) {
      bh[nt] = *(const short8*)(WtH + wbase + (size_t)(16 * nt) * Cc);
      bl[nt] = *(const short8*)(WtL + wbase + (size_t)(16 * nt) * Cc);
    }

    // ---- MFMA: acc += ah*bh + ah*bl ----
    #pragma unroll
    for (int nt = 0; nt < 4; ++nt)
      #pragma unroll
      for (int mt = 0; mt < 4; ++mt) {
        acc[mt][nt] = __builtin_amdgcn_mfma_f32_16x16x32_bf16(ah[mt], bh[nt], acc[mt][nt], 0, 0, 0);
        acc[mt][nt] = __builtin_amdgcn_mfma_f32_16x16x32_bf16(ah[mt], bl[nt], acc[mt][nt], 0, 0, 0);
      }

    // ---- convert prefetched chunk, write other buffer (safe: its readers
    //      finished before the barrier that ended iter kc-1) ----
    if (kc < 7) {
      #pragma unroll
      for (int qq = 0; qq < 4; ++qq) {
        uint2 hh;
        hh.x = (unsigned)f2bf(xn[qq].x) | ((unsigned)f2bf(xn[qq].y) << 16);
        hh.y = (unsigned)f2bf(xn[qq].z) | ((unsigned)f2bf(xn[qq].w) << 16);
        *(uint2*)&sXh[1 - cur][rr][hf * 16 + 4 * qq] = hh;
      }
      __syncthreads();
    }
  }

  // ---- epilogue: score[r] = sum_col tanh(h)*w2[col] ----
  float w2v[4];
  #pragma unroll
  for (int nt = 0; nt < 4; ++nt) w2v[nt] = w2[64 * wc + 16 * nt + ln];

  float p[4][4];
  #pragma unroll
  for (int mt = 0; mt < 4; ++mt)
    #pragma unroll
    for (int r = 0; r < 4; ++r) p[mt][r] = 0.f;

  #pragma unroll
  for (int mt = 0; mt < 4; ++mt)
    #pragma unroll
    for (int nt = 0; nt < 4; ++nt)
      #pragma unroll
      for (int r = 0; r < 4; ++r)
        p[mt][r] += fast_tanh(acc[mt][nt][r]) * w2v[nt];

  #pragma unroll
  for (int off = 1; off < 16; off <<= 1)
    #pragma unroll
    for (int mt = 0; mt < 4; ++mt)
      #pragma unroll
      for (int r = 0; r < 4; ++r)
        p[mt][r] += __shfl_xor(p[mt][r], off);

  __syncthreads();   // all LDS frag reads done before sScore aliasing concerns
  if (ln == 0) {
    #pragma unroll
    for (int mt = 0; mt < 4; ++mt)
      #pragma unroll
      for (int r = 0; r < 4; ++r)
        sScore[wc][64 * wr + 16 * mt + 4 * q + r] = p[mt][r];
  }
  __syncthreads();

  // ---- block-local softmax partials ----
  if (tid < BM) sP[tid] = sScore[0][tid] + sScore[1][tid];
  __syncthreads();
  if (w == 0) {
    float a = sP[lane], b = sP[lane + 64];
    float m = fmaxf(a, b);
    #pragma unroll
    for (int off = 1; off < 64; off <<= 1) m = fmaxf(m, __shfl_xor(m, off));
    float e0 = __expf(a - m), e1 = __expf(b - m);
    sP[lane] = e0; sP[lane + 64] = e1;
    float s = e0 + e1;
    #pragma unroll
    for (int off = 1; off < 64; off <<= 1) s += __shfl_xor(s, off);
    if (lane == 0) { sMB = m; sLB = s; }
  }
  __syncthreads();

  // ---- weighted x partial: o[c] = sum_r sP[r] * x[row0+r][c] (L2/L3-hot re-read) ----
  const int c4 = tid & 63;
  const int rg = tid >> 6;
  const float* xo = x + (size_t)(row0 + rg * 32) * Cc + c4 * 4;
  float4 o = make_float4(0.f, 0.f, 0.f, 0.f);
  #pragma unroll 4
  for (int r = 0; r < 32; ++r) {
    float pw = sP[rg * 32 + r];
    float4 xv = *(const float4*)(xo + (size_t)r * Cc);
    o.x = fmaf(pw, xv.x, o.x);
    o.y = fmaf(pw, xv.y, o.y);
    o.z = fmaf(pw, xv.z, o.z);
    o.w = fmaf(pw, xv.w, o.w);
  }
  *(float4*)&sO[rg][c4 * 4] = o;
  __syncthreads();

  float oc = sO[0][tid] + sO[1][tid] + sO[2][tid] + sO[3][tid];
  oPart[(size_t)blockIdx.x * Cc + tid] = oc;
  if (tid == 0) { mPart[blockIdx.x] = sMB; lPart[blockIdx.x] = sLB; }
}

// ---- combine 64 block partials per batch (deterministic) ----
__global__ __launch_bounds__(256) void combine_kernel(
    const float* __restrict__ oPart, const float* __restrict__ mPart,
    const float* __restrict__ lPart, float* __restrict__ out)
{
  const int b = blockIdx.x;
  const int t = threadIdx.x;
  float M = -3.4e38f;
  for (int k = 0; k < BPB; ++k) M = fmaxf(M, mPart[b * BPB + k]);
  float num = 0.f, den = 0.f;
  for (int k = 0; k < BPB; ++k) {
    float wgt = __expf(mPart[b * BPB + k] - M);
    den += wgt * lPart[b * BPB + k];
    num = fmaf(wgt, oPart[(size_t)(b * BPB + k) * Cc + t], num);
  }
  out[b * Cc + t] = num / den;
}

extern "C" void kernel_launch(void* const* d_in, const int* in_sizes, int n_in,
                              void* d_out, int out_size, void* d_ws, size_t ws_size,
                              hipStream_t stream)
{
  const float* x  = (const float*)d_in[0];
  const float* W1 = (const float*)d_in[1];
  const float* b1 = (const float*)d_in[2];
  const float* w2 = (const float*)d_in[3];
  // d_in[4] = b2: unused (softmax shift-invariant)
  float* out = (float*)d_out;

  u16*   WtH   = (u16*)d_ws;                                   // 64 KB
  u16*   WtL   = WtH + MIDm * Cc;                              // 64 KB
  float* oPart = (float*)((char*)d_ws + 131072);               // 2 MB
  float* mPart = (float*)((char*)d_ws + 131072 + 2097152);     // 8 KB
  float* lPart = (float*)((char*)d_ws + 131072 + 2097152 + 8192);

  wprep_kernel<<<MIDm, Cc, 0, stream>>>(W1, WtH, WtL);
  fused_kernel<<<NBLK, 256, 0, stream>>>(x, WtH, WtL, b1, w2, oPart, mPart, lPart);
  combine_kernel<<<Bb, Cc, 0, stream>>>(oPart, mPart, lPart, out);
}

// Round 4
// 97.346 us; speedup vs baseline: 3.1876x; 1.3745x over previous
//
#include <hip/hip_runtime.h>
#include <hip/hip_bf16.h>

// AttentivePooling: B=32, S=8192, C=256, MID=128, fp32 in/out.
// out[b,c] = sum_s softmax_s( tanh(x@W1+b1)@w2 )[b,s] * x[b,s,c]   (b2 shift-invariant)
//
// R4: global_load_lds DMA staging of fp32 x (double-buffered, 32KB chunks,
// pre-swizzled global source so LDS reads are bank-conflict-free), 1-term
// bf16 MFMA (x_hi * W_hi), frag-major precomputed W fragments in registers.

typedef __attribute__((ext_vector_type(8))) short short8;
typedef __attribute__((ext_vector_type(4))) float f32x4;
typedef unsigned short u16;

constexpr int Bb = 32;
constexpr int Ss = 8192;
constexpr int Cc = 256;
constexpr int MIDm = 128;
constexpr int BM = 128;              // rows per block
constexpr int BK = 64;               // k-chunk (fp32 cols)
constexpr int NCH = Cc / BK;         // 4 chunks
constexpr int NBLK = Bb * Ss / BM;   // 2048
constexpr int BPB = Ss / BM;         // 64 blocks per batch

__device__ __forceinline__ u16 f2bf(float f) {
  return __builtin_bit_cast(u16, __float2bfloat16(f));   // RNE, cvt_pk-friendly
}

// ---- one-time prep: W fragments, frag-major so fused loads are coalesced ----
// FB[t] for t = wc*2048 + kc*512 + kg*256 + nt*64 + lane  -> 8 bf16 (16B):
//   n = wc*64 + nt*16 + (lane&15),  k = kc*64 + kg*32 + (lane>>4)*8 + e
__global__ __launch_bounds__(256) void wprep_kernel(
    const float* __restrict__ W1, u16* __restrict__ FB)
{
  const int t    = blockIdx.x * 256 + threadIdx.x;   // 0..4095
  const int lane = t & 63;
  const int nt   = (t >> 6) & 3;
  const int kg   = (t >> 8) & 1;
  const int kc   = (t >> 9) & 3;
  const int wc   = (t >> 11) & 1;
  const int n    = wc * 64 + nt * 16 + (lane & 15);
  const int k0   = kc * 64 + kg * 32 + (lane >> 4) * 8;
  union { u16 v[8]; short8 s; } u;
  #pragma unroll
  for (int e = 0; e < 8; ++e) u.v[e] = f2bf(W1[(size_t)(k0 + e) * MIDm + n]);
  *(short8*)(FB + (size_t)t * 8) = u.s;
}

// ---- fused: MFMA scores -> block softmax partials -> weighted x partial ----
__global__ __launch_bounds__(256, 2) void fused_kernel(
    const float* __restrict__ x, const u16* __restrict__ FB,
    const float* __restrict__ b1, const float* __restrict__ w2,
    float* __restrict__ oPart, float* __restrict__ mPart, float* __restrict__ lPart)
{
  __shared__ __align__(16) float sX[2][BM * BK];   // 2 x 32KB, swizzled layout
  __shared__ float sScore[2][BM];
  __shared__ float sP[BM];
  __shared__ float sMB, sLB;
  __shared__ __align__(16) float sO[4][Cc];

  const int tid  = threadIdx.x;
  const int lane = tid & 63;
  const int w    = tid >> 6;
  const int wr   = w >> 1;
  const int wc   = w & 1;
  const int q    = lane >> 4;
  const int ln   = lane & 15;
  const int row0 = blockIdx.x * BM;

  // acc init with b1[col]
  f32x4 acc[4][4];
  #pragma unroll
  for (int nt = 0; nt < 4; ++nt) {
    float bj = b1[64 * wc + 16 * nt + ln];
    #pragma unroll
    for (int mt = 0; mt < 4; ++mt) {
      acc[mt][nt][0] = bj; acc[mt][nt][1] = bj; acc[mt][nt][2] = bj; acc[mt][nt][3] = bj;
    }
  }

  const u16* fb = FB + ((size_t)wc * 2048 + lane) * 8;
  // LDFRAG(kc,kg,nt): FB[(wc*2048 + kc*512 + kg*256 + nt*64 + lane)*8]
  #define LDFRAG(kc, kg, nt) (*(const short8*)(fb + ((size_t)(kc)*512 + (kg)*256 + (nt)*64) * 8))

  // STAGE chunk kc of x into buffer buf via async DMA, pre-swizzled source.
  // LDS byte L holds x[row][ (L&255) ^ ((row&7)<<4) ] of the chunk (row = L>>8).
  #define STAGE(buf, kc)                                                              \
    {                                                                                 \
      _Pragma("unroll")                                                               \
      for (int r = 0; r < 8; ++r) {                                                   \
        int L    = r * 4096 + tid * 16;                                               \
        int row  = L >> 8;                                                            \
        int colb = (L & 255) ^ ((row & 7) << 4);                                      \
        const char* src = (const char*)x                                              \
            + ((size_t)(row0 + row) * Cc + (kc) * BK) * 4 + colb;                     \
        __builtin_amdgcn_global_load_lds(                                             \
            (const __attribute__((address_space(1))) void*)src,                       \
            (__attribute__((address_space(3))) void*)((char*)&sX[buf][0] + L),        \
            16, 0, 0);                                                                \
      }                                                                               \
    }

  short8 bfr[2][8];   // ping-pong B fragments [buf][kg*4+nt]

  // prologue
  STAGE(0, 0);
  #pragma unroll
  for (int i = 0; i < 8; ++i) bfr[0][i] = LDFRAG(0, i >> 2, i & 3);
  __syncthreads();

  #pragma unroll
  for (int kc = 0; kc < NCH; ++kc) {
    const int cur = kc & 1;
    if (kc < NCH - 1) {
      STAGE(1 - cur, kc + 1);
      #pragma unroll
      for (int i = 0; i < 8; ++i) bfr[1 - cur][i] = LDFRAG(kc + 1, i >> 2, i & 3);
    }

    #pragma unroll
    for (int kg = 0; kg < 2; ++kg) {
      short8 af[4];
      #pragma unroll
      for (int mt = 0; mt < 4; ++mt) {
        const int row = 64 * wr + 16 * mt + ln;
        const int s   = (row & 7) << 4;
        const int c   = kg * 128 + q * 32;
        const char* base = (const char*)&sX[cur][0] + row * 256;
        float4 lo = *(const float4*)(base + ((c) ^ s));
        float4 hi = *(const float4*)(base + ((c + 16) ^ s));
        union { u16 v[8]; short8 s8; } t8;
        t8.v[0] = f2bf(lo.x); t8.v[1] = f2bf(lo.y); t8.v[2] = f2bf(lo.z); t8.v[3] = f2bf(lo.w);
        t8.v[4] = f2bf(hi.x); t8.v[5] = f2bf(hi.y); t8.v[6] = f2bf(hi.z); t8.v[7] = f2bf(hi.w);
        af[mt] = t8.s8;
      }
      #pragma unroll
      for (int nt = 0; nt < 4; ++nt)
        #pragma unroll
        for (int mt = 0; mt < 4; ++mt)
          acc[mt][nt] = __builtin_amdgcn_mfma_f32_16x16x32_bf16(
              af[mt], bfr[cur][kg * 4 + nt], acc[mt][nt], 0, 0, 0);
    }
    if (kc < NCH - 1) __syncthreads();
  }

  // ---- epilogue: score[r] = sum_col tanh(h)*w2[col] ----
  float w2v[4];
  #pragma unroll
  for (int nt = 0; nt < 4; ++nt) w2v[nt] = w2[64 * wc + 16 * nt + ln];

  float p[4][4];
  #pragma unroll
  for (int mt = 0; mt < 4; ++mt)
    #pragma unroll
    for (int r = 0; r < 4; ++r) p[mt][r] = 0.f;

  #pragma unroll
  for (int mt = 0; mt < 4; ++mt)
    #pragma unroll
    for (int nt = 0; nt < 4; ++nt)
      #pragma unroll
      for (int r = 0; r < 4; ++r)
        p[mt][r] += (1.0f - 2.0f / (__expf(2.0f * acc[mt][nt][r]) + 1.0f)) * w2v[nt];

  #pragma unroll
  for (int off = 1; off < 16; off <<= 1)
    #pragma unroll
    for (int mt = 0; mt < 4; ++mt)
      #pragma unroll
      for (int r = 0; r < 4; ++r)
        p[mt][r] += __shfl_xor(p[mt][r], off);

  __syncthreads();
  if (ln == 0) {
    #pragma unroll
    for (int mt = 0; mt < 4; ++mt)
      #pragma unroll
      for (int r = 0; r < 4; ++r)
        sScore[wc][64 * wr + 16 * mt + 4 * q + r] = p[mt][r];
  }
  __syncthreads();

  // ---- block-local softmax partials ----
  if (tid < BM) sP[tid] = sScore[0][tid] + sScore[1][tid];
  __syncthreads();
  if (w == 0) {
    float a = sP[lane], b = sP[lane + 64];
    float m = fmaxf(a, b);
    #pragma unroll
    for (int off = 1; off < 64; off <<= 1) m = fmaxf(m, __shfl_xor(m, off));
    float e0 = __expf(a - m), e1 = __expf(b - m);
    sP[lane] = e0; sP[lane + 64] = e1;
    float s = e0 + e1;
    #pragma unroll
    for (int off = 1; off < 64; off <<= 1) s += __shfl_xor(s, off);
    if (lane == 0) { sMB = m; sLB = s; }
  }
  __syncthreads();

  // ---- weighted x partial: o[c] = sum_r sP[r] * x[row0+r][c]  (L2-hot re-read) ----
  const int c4 = tid & 63;
  const int rg = tid >> 6;
  const float* xo = x + (size_t)(row0 + rg * 32) * Cc + c4 * 4;
  float4 o = make_float4(0.f, 0.f, 0.f, 0.f);
  #pragma unroll 8
  for (int r = 0; r < 32; ++r) {
    float pw = sP[rg * 32 + r];
    float4 xv = *(const float4*)(xo + (size_t)r * Cc);
    o.x = fmaf(pw, xv.x, o.x);
    o.y = fmaf(pw, xv.y, o.y);
    o.z = fmaf(pw, xv.z, o.z);
    o.w = fmaf(pw, xv.w, o.w);
  }
  *(float4*)&sO[rg][c4 * 4] = o;
  __syncthreads();

  float oc = sO[0][tid] + sO[1][tid] + sO[2][tid] + sO[3][tid];
  oPart[(size_t)blockIdx.x * Cc + tid] = oc;
  if (tid == 0) { mPart[blockIdx.x] = sMB; lPart[blockIdx.x] = sLB; }
}

// ---- combine 64 block partials per batch (deterministic) ----
__global__ __launch_bounds__(256) void combine_kernel(
    const float* __restrict__ oPart, const float* __restrict__ mPart,
    const float* __restrict__ lPart, float* __restrict__ out)
{
  const int b = blockIdx.x;
  const int t = threadIdx.x;
  float M = -3.4e38f;
  for (int k = 0; k < BPB; ++k) M = fmaxf(M, mPart[b * BPB + k]);
  float num = 0.f, den = 0.f;
  for (int k = 0; k < BPB; ++k) {
    float wgt = __expf(mPart[b * BPB + k] - M);
    den += wgt * lPart[b * BPB + k];
    num = fmaf(wgt, oPart[(size_t)(b * BPB + k) * Cc + t], num);
  }
  out[b * Cc + t] = num / den;
}

extern "C" void kernel_launch(void* const* d_in, const int* in_sizes, int n_in,
                              void* d_out, int out_size, void* d_ws, size_t ws_size,
                              hipStream_t stream)
{
  const float* x  = (const float*)d_in[0];
  const float* W1 = (const float*)d_in[1];
  const float* b1 = (const float*)d_in[2];
  const float* w2 = (const float*)d_in[3];
  // d_in[4] = b2: unused (softmax shift-invariant)
  float* out = (float*)d_out;

  u16*   FB    = (u16*)d_ws;                                  // 64 KB frag-major W
  float* oPart = (float*)((char*)d_ws + 65536);               // 2 MB
  float* mPart = (float*)((char*)d_ws + 65536 + 2097152);     // 8 KB
  float* lPart = (float*)((char*)d_ws + 65536 + 2097152 + 8192);

  wprep_kernel<<<16, 256, 0, stream>>>(W1, FB);
  fused_kernel<<<NBLK, 256, 0, stream>>>(x, FB, b1, w2, oPart, mPart, lPart);
  combine_kernel<<<Bb, Cc, 0, stream>>>(oPart, mPart, lPart, out);
}